// Round 1
// baseline (2286.906 us; speedup 1.0000x reference)
//
#include <hip/hip_runtime.h>
#include <math.h>

#define B_  256
#define N_  80
#define C_  1024
#define CO_ 1024

__device__ __forceinline__ float leaky(float v){ return v >= 0.f ? v : 0.2f * v; }
__device__ __forceinline__ float sigmoidf_(float v){ return 1.f / (1.f + __expf(-v)); }

// ---------------- K1: adj_s = D^-1/2 A^T D^-1/2 ----------------
__global__ void k_adj(const float* __restrict__ A, float* __restrict__ adj){
    __shared__ float d[N_];
    int t = threadIdx.x;
    if (t < N_){
        float s = 0.f;
        for (int j = 0; j < N_; j++) s += A[t * N_ + j];
        d[t] = rsqrtf(s);
    }
    __syncthreads();
    for (int idx = t; idx < N_ * N_; idx += blockDim.x){
        int i = idx / N_, j = idx % N_;
        adj[idx] = d[i] * A[j * N_ + i] * d[j];
    }
}

// ---------------- K2: h1 = leaky(adj_s @ x[b]) ----------------
// grid (B, C/256), 256 threads
__global__ __launch_bounds__(256) void k_prop_static(const float* __restrict__ x,
                                                     const float* __restrict__ adj,
                                                     float* __restrict__ h){
    __shared__ float xs[N_][256];     // 80 KB
    __shared__ float al[N_ * N_];     // 25.6 KB
    int b = blockIdx.x, c0 = blockIdx.y * 256, tc = threadIdx.x;
    const float* xb = x + (size_t)b * N_ * C_;
    for (int j = 0; j < N_; j++) xs[j][tc] = xb[j * C_ + c0 + tc];
    for (int idx = tc; idx < N_ * N_; idx += 256) al[idx] = adj[idx];
    __syncthreads();
    float* hb = h + (size_t)b * N_ * C_ + c0 + tc;
    for (int i = 0; i < N_; i++){
        float acc = 0.f;
        #pragma unroll 8
        for (int j = 0; j < N_; j++) acc += al[i * N_ + j] * xs[j][tc];
        hb[i * C_] = leaky(acc);
    }
}

// ---------------- K3/K13: tiled fp32 GEMM, Out = epi(A @ W [+Res]) --------
// A: [M,1024] row-major, W: [1024,1024] row-major. 64x64 tile, BK=16.
// EPI 0: Out = Res + A@W ; EPI 1: Out = leaky(A@W)
#define PAD 68
template<int EPI>
__global__ __launch_bounds__(256) void k_gemm_nn(const float* __restrict__ Am,
                                                 const float* __restrict__ W,
                                                 const float* __restrict__ Res,
                                                 float* __restrict__ Out, int M){
    __shared__ float As[16][PAD];
    __shared__ float Bs[16][PAD];
    int tid = threadIdx.x;
    int tx = tid & 15, ty = tid >> 4;
    int row0 = blockIdx.y * 64, col0 = blockIdx.x * 64;
    float acc[4][4] = {};
    int lr = tid >> 2;          // 0..63
    int lk = (tid & 3) * 4;     // 0,4,8,12
    int kb = tid >> 4, cb = (tid & 15) * 4;
    for (int k0 = 0; k0 < C_; k0 += 16){
        float4 av = *(const float4*)(Am + (size_t)(row0 + lr) * C_ + k0 + lk);
        float4 bv = *(const float4*)(W  + (size_t)(k0 + kb) * C_ + col0 + cb);
        As[lk + 0][lr] = av.x; As[lk + 1][lr] = av.y;
        As[lk + 2][lr] = av.z; As[lk + 3][lr] = av.w;
        *(float4*)&Bs[kb][cb] = bv;
        __syncthreads();
        #pragma unroll
        for (int kk = 0; kk < 16; kk++){
            float4 a  = *(const float4*)&As[kk][ty * 4];
            float4 bb = *(const float4*)&Bs[kk][tx * 4];
            float ar[4] = {a.x, a.y, a.z, a.w};
            float br[4] = {bb.x, bb.y, bb.z, bb.w};
            #pragma unroll
            for (int i = 0; i < 4; i++)
                #pragma unroll
                for (int j = 0; j < 4; j++) acc[i][j] += ar[i] * br[j];
        }
        __syncthreads();
    }
    for (int i = 0; i < 4; i++){
        int r = row0 + ty * 4 + i;
        for (int j = 0; j < 4; j++){
            int cl = col0 + tx * 4 + j;
            size_t o = (size_t)r * C_ + cl;
            float v = acc[i][j];
            if (EPI == 0) v += Res[o];
            else          v = leaky(v);
            Out[o] = v;
        }
    }
}

// ---------------- K5: Out = A @ W^T + bias  (M x 1024, W rows are output cols)
__global__ __launch_bounds__(256) void k_gemm_bt_bias(const float* __restrict__ Am,
                                                      const float* __restrict__ W,
                                                      const float* __restrict__ bias,
                                                      float* __restrict__ Out, int M){
    __shared__ float As[16][PAD];
    __shared__ float Bs[16][PAD];
    int tid = threadIdx.x;
    int tx = tid & 15, ty = tid >> 4;
    int row0 = blockIdx.y * 64, col0 = blockIdx.x * 64;
    float acc[4][4] = {};
    int lr = tid >> 2;
    int lk = (tid & 3) * 4;
    for (int k0 = 0; k0 < C_; k0 += 16){
        float4 av = *(const float4*)(Am + (size_t)(row0 + lr) * C_ + k0 + lk);
        float4 wv = *(const float4*)(W  + (size_t)(col0 + lr) * C_ + k0 + lk);
        As[lk + 0][lr] = av.x; As[lk + 1][lr] = av.y;
        As[lk + 2][lr] = av.z; As[lk + 3][lr] = av.w;
        Bs[lk + 0][lr] = wv.x; Bs[lk + 1][lr] = wv.y;
        Bs[lk + 2][lr] = wv.z; Bs[lk + 3][lr] = wv.w;
        __syncthreads();
        #pragma unroll
        for (int kk = 0; kk < 16; kk++){
            float4 a  = *(const float4*)&As[kk][ty * 4];
            float4 bb = *(const float4*)&Bs[kk][tx * 4];
            float ar[4] = {a.x, a.y, a.z, a.w};
            float br[4] = {bb.x, bb.y, bb.z, bb.w};
            #pragma unroll
            for (int i = 0; i < 4; i++)
                #pragma unroll
                for (int j = 0; j < 4; j++) acc[i][j] += ar[i] * br[j];
        }
        __syncthreads();
    }
    for (int i = 0; i < 4; i++){
        int r = row0 + ty * 4 + i;
        for (int j = 0; j < 4; j++){
            int cl = col0 + tx * 4 + j;
            Out[(size_t)r * C_ + cl] = acc[i][j] + bias[cl];
        }
    }
}

// ---------------- K4: glb0[b,c] = mean_n x2[b,n,c] ----------------
__global__ void k_pool(const float* __restrict__ x2, float* __restrict__ glb0){
    int b = blockIdx.x, c = blockIdx.y * 256 + threadIdx.x;
    const float* p = x2 + (size_t)b * N_ * C_ + c;
    float s = 0.f;
    for (int nn = 0; nn < N_; nn++) s += p[nn * C_];
    glb0[b * C_ + c] = s * (1.f / N_);
}

// ---------------- K6: BN stats over batch ----------------
__global__ void k_bnstat(const float* __restrict__ g, float* __restrict__ mu,
                         float* __restrict__ rstd){
    int c = blockIdx.x * 256 + threadIdx.x;
    float s = 0.f, s2 = 0.f;
    for (int b = 0; b < B_; b++){ float v = g[b * C_ + c]; s += v; s2 += v * v; }
    float m = s * (1.f / B_);
    float var = s2 * (1.f / B_) - m * m;
    mu[c] = m;
    rstd[c] = rsqrtf(var + 1e-5f);
}

// ---------------- K7: glb2 = leaky(BN(glb1)) ----------------
__global__ void k_bnapply(const float* __restrict__ g, const float* __restrict__ mu,
                          const float* __restrict__ rstd, const float* __restrict__ gamma,
                          const float* __restrict__ beta, float* __restrict__ o){
    int i = blockIdx.x * 256 + threadIdx.x;
    int c = i & (C_ - 1);
    float v = (g[i] - mu[c]) * rstd[c] * gamma[c] + beta[c];
    o[i] = leaky(v);
}

// ---------------- K8: g1[b,n] = W1[n]·glb2[b] + ccb[n] ----------------
__global__ __launch_bounds__(256) void k_g1(const float* __restrict__ glb2,
                                            const float* __restrict__ ccw,
                                            const float* __restrict__ ccb,
                                            float* __restrict__ g1){
    __shared__ float gs[C_];
    int b = blockIdx.x, tid = threadIdx.x;
    for (int i = tid; i < C_; i += 256) gs[i] = glb2[b * C_ + i];
    __syncthreads();
    int w = tid >> 6, lane = tid & 63;
    for (int n = w; n < N_; n += 4){
        const float* wr = ccw + (size_t)n * (2 * C_);
        float acc = 0.f;
        for (int c = lane; c < C_; c += 64) acc += gs[c] * wr[c];
        for (int off = 32; off; off >>= 1) acc += __shfl_down(acc, off);
        if (lane == 0) g1[b * N_ + n] = acc + ccb[n];
    }
}

// ---------------- K9: dyn[b,n,m] = sigmoid(g1[b,n] + W2[n]·x2[b,m]) -------
__global__ __launch_bounds__(256) void k_dyn(const float* __restrict__ x2,
                                             const float* __restrict__ ccw,
                                             const float* __restrict__ g1,
                                             float* __restrict__ dyn){
    __shared__ float Ws[N_][33];
    __shared__ float Xs[N_][33];
    int b = blockIdx.x, tid = threadIdx.x;
    int tx = tid & 15, ty = tid >> 4;
    float acc[5][5] = {};
    const float* xb = x2 + (size_t)b * N_ * C_;
    for (int k0 = 0; k0 < C_; k0 += 32){
        for (int idx = tid; idx < N_ * 32; idx += 256){
            int n = idx >> 5, kk = idx & 31;
            Ws[n][kk] = ccw[(size_t)n * (2 * C_) + C_ + k0 + kk];
            Xs[n][kk] = xb[(size_t)n * C_ + k0 + kk];
        }
        __syncthreads();
        #pragma unroll 8
        for (int kk = 0; kk < 32; kk++){
            float a[5], bb[5];
            #pragma unroll
            for (int i = 0; i < 5; i++) a[i] = Ws[ty * 5 + i][kk];
            #pragma unroll
            for (int j = 0; j < 5; j++) bb[j] = Xs[tx * 5 + j][kk];
            #pragma unroll
            for (int i = 0; i < 5; i++)
                #pragma unroll
                for (int j = 0; j < 5; j++) acc[i][j] += a[i] * bb[j];
        }
        __syncthreads();
    }
    for (int i = 0; i < 5; i++){
        int n = ty * 5 + i;
        float gg = g1[b * N_ + n];
        for (int j = 0; j < 5; j++){
            int m = tx * 5 + j;
            dyn[(size_t)b * N_ * N_ + n * N_ + m] = sigmoidf_(acc[i][j] + gg);
        }
    }
}

// ---------------- K10: loss rows + dinv ----------------
__global__ __launch_bounds__(128) void k_lossrow(const float* __restrict__ out1,
                                                 const float* __restrict__ dyn,
                                                 float* __restrict__ dinv,
                                                 float* __restrict__ lossp){
    __shared__ float o1s[N_];
    __shared__ float dd[N_];
    int b = blockIdx.x, t = threadIdx.x;
    if (t < N_) o1s[t] = sigmoidf_(out1[b * N_ + t]);
    __syncthreads();
    const float* db = dyn + (size_t)b * N_ * N_;
    if (t < N_){
        float acc = 0.f;                       // column m = t
        for (int nn = 0; nn < N_; nn++) acc += o1s[nn] * db[nn * N_ + t];
        float tt = acc * (1.f / N_);
        float diff = o1s[t] - tt;
        dd[t] = diff * diff;
        float rs = 0.f;                        // row n = t
        for (int m = 0; m < N_; m++) rs += db[t * N_ + m];
        dinv[b * N_ + t] = rsqrtf(rs);
    }
    __syncthreads();
    if (t == 0){
        float s = 0.f;
        for (int m = 0; m < N_; m++) s += dd[m];
        lossp[b] = sqrtf(s);
    }
}

// ---------------- K11: loss = sum(lossp) ----------------
__global__ void k_lsum(const float* __restrict__ lossp, float* __restrict__ out_loss){
    float v = lossp[threadIdx.x];
    for (int off = 32; off; off >>= 1) v += __shfl_down(v, off);
    __shared__ float wsum[4];
    int lane = threadIdx.x & 63, w = threadIdx.x >> 6;
    if (lane == 0) wsum[w] = v;
    __syncthreads();
    if (threadIdx.x == 0) out_loss[0] = wsum[0] + wsum[1] + wsum[2] + wsum[3];
}

// ---------------- K12: h2 = leaky(adjs @ x2) ----------------
__global__ __launch_bounds__(256) void k_prop_dyn(const float* __restrict__ x2,
                                                  const float* __restrict__ dyn,
                                                  const float* __restrict__ dinv,
                                                  float* __restrict__ h){
    __shared__ float xs[N_][256];   // pre-scaled by dinv[j]
    __shared__ float dl[N_ * N_];
    __shared__ float di[N_];
    int b = blockIdx.x, c0 = blockIdx.y * 256, tc = threadIdx.x;
    const float* xb = x2 + (size_t)b * N_ * C_;
    if (tc < N_) di[tc] = dinv[b * N_ + tc];
    for (int idx = tc; idx < N_ * N_; idx += 256) dl[idx] = dyn[(size_t)b * N_ * N_ + idx];
    __syncthreads();
    for (int j = 0; j < N_; j++) xs[j][tc] = xb[j * C_ + c0 + tc] * di[j];
    __syncthreads();
    float* hb = h + (size_t)b * N_ * C_ + c0 + tc;
    for (int i = 0; i < N_; i++){
        float acc = 0.f;
        #pragma unroll 8
        for (int j = 0; j < N_; j++) acc += dl[j * N_ + i] * xs[j][tc];
        hb[i * C_] = leaky(di[i] * acc);
    }
}

extern "C" void kernel_launch(void* const* d_in, const int* in_sizes, int n_in,
                              void* d_out, int out_size, void* d_ws, size_t ws_size,
                              hipStream_t stream) {
    const float* x     = (const float*)d_in[0];
    const float* out1  = (const float*)d_in[1];
    const float* A     = (const float*)d_in[2];
    const float* sw    = (const float*)d_in[3];
    const float* cgw   = (const float*)d_in[4];
    const float* cgb   = (const float*)d_in[5];
    const float* gamma = (const float*)d_in[6];
    const float* beta  = (const float*)d_in[7];
    const float* ccw   = (const float*)d_in[8];
    const float* ccb   = (const float*)d_in[9];
    const float* dw    = (const float*)d_in[10];
    float* out = (float*)d_out;
    float* ws  = (float*)d_ws;

    const size_t XN = (size_t)B_ * N_ * C_;   // 20,971,520
    float* X2   = ws;                          // 84 MB
    float* H    = X2   + XN;                   // 84 MB (h1 then h2)
    float* ADJ  = H    + XN;                   // 6400
    float* GLB0 = ADJ  + N_ * N_;              // B*C
    float* GLB1 = GLB0 + (size_t)B_ * C_;
    float* GLB2 = GLB1 + (size_t)B_ * C_;
    float* MU   = GLB2 + (size_t)B_ * C_;
    float* RSTD = MU   + C_;
    float* G1   = RSTD + C_;                   // B*N
    float* DYN  = G1   + (size_t)B_ * N_;      // B*N*N
    float* DINV = DYN  + (size_t)B_ * N_ * N_;
    float* LOSSP= DINV + (size_t)B_ * N_;      // B
    // total ~177.7 MB

    const int M = B_ * N_;                     // 20480

    k_adj<<<1, 128, 0, stream>>>(A, ADJ);
    k_prop_static<<<dim3(B_, C_ / 256), 256, 0, stream>>>(x, ADJ, H);
    k_gemm_nn<0><<<dim3(C_ / 64, M / 64), 256, 0, stream>>>(H, sw, x, X2, M);
    k_pool<<<dim3(B_, C_ / 256), 256, 0, stream>>>(X2, GLB0);
    k_gemm_bt_bias<<<dim3(C_ / 64, B_ / 64), 256, 0, stream>>>(GLB0, cgw, cgb, GLB1, B_);
    k_bnstat<<<C_ / 256, 256, 0, stream>>>(GLB1, MU, RSTD);
    k_bnapply<<<(B_ * C_) / 256, 256, 0, stream>>>(GLB1, MU, RSTD, gamma, beta, GLB2);
    k_g1<<<B_, 256, 0, stream>>>(GLB2, ccw, ccb, G1);
    k_dyn<<<B_, 256, 0, stream>>>(X2, ccw, G1, DYN);
    k_lossrow<<<B_, 128, 0, stream>>>(out1, DYN, DINV, LOSSP);
    k_lsum<<<1, 256, 0, stream>>>(LOSSP, out + (size_t)B_ * N_ * CO_);
    k_prop_dyn<<<dim3(B_, C_ / 256), 256, 0, stream>>>(X2, DYN, DINV, H);
    k_gemm_nn<1><<<dim3(CO_ / 64, M / 64), 256, 0, stream>>>(H, dw, nullptr, out, M);
}

// Round 2
// 1312.499 us; speedup vs baseline: 1.7424x; 1.7424x over previous
//
#include <hip/hip_runtime.h>
#include <hip/hip_bf16.h>
#include <math.h>

#define B_  256
#define N_  80
#define C_  1024
#define CO_ 1024

typedef __hip_bfloat16 bf16;
using bf16x8 = __attribute__((ext_vector_type(8))) short;   // 8 bf16 = 4 VGPRs
using f32x4  = __attribute__((ext_vector_type(4))) float;

__device__ __forceinline__ float leaky(float v){ return v >= 0.f ? v : 0.2f * v; }
__device__ __forceinline__ float sigmoidf_(float v){ return 1.f / (1.f + __expf(-v)); }

__device__ __forceinline__ void gll16(const void* g, void* l){
    __builtin_amdgcn_global_load_lds(
        (const __attribute__((address_space(1))) void*)g,
        (__attribute__((address_space(3))) void*)l, 16, 0, 0);
}

// ---------------- K0: transpose + convert weight: WT[n][k] = bf16(W[k][n]) ----
__global__ __launch_bounds__(256) void k_convT(const float* __restrict__ W, bf16* __restrict__ WT){
    __shared__ float t[32][33];
    int k0 = blockIdx.y * 32, n0 = blockIdx.x * 32;
    int tx = threadIdx.x & 31, ty = threadIdx.x >> 5;
    for (int i = ty; i < 32; i += 8) t[i][tx] = W[(size_t)(k0 + i) * 1024 + n0 + tx];
    __syncthreads();
    for (int i = ty; i < 32; i += 8)
        WT[(size_t)(n0 + i) * 1024 + k0 + tx] = __float2bfloat16(t[tx][i]);
}

// ---------------- K1: adj_s = D^-1/2 A^T D^-1/2 ----------------
__global__ void k_adj(const float* __restrict__ A, float* __restrict__ adj){
    __shared__ float d[N_];
    int t = threadIdx.x;
    if (t < N_){
        float s = 0.f;
        for (int j = 0; j < N_; j++) s += A[t * N_ + j];
        d[t] = rsqrtf(s);
    }
    __syncthreads();
    for (int idx = t; idx < N_ * N_; idx += blockDim.x){
        int i = idx / N_, j = idx % N_;
        adj[idx] = d[i] * A[j * N_ + i] * d[j];
    }
}

// ---------------- K2: h1 = bf16(leaky(adj_s @ x[b])), register-resident ------
// grid (B, C/256), 256 threads; x column in 80 VGPRs, adj via scalar loads.
__global__ __launch_bounds__(256) void k_prop_static(const float* __restrict__ x,
                                                     const float* __restrict__ adj,
                                                     bf16* __restrict__ h){
    int b = blockIdx.x, c = blockIdx.y * 256 + threadIdx.x;
    const float* xb = x + (size_t)b * N_ * C_ + c;
    float xr[N_];
    #pragma unroll
    for (int j = 0; j < N_; j++) xr[j] = xb[(size_t)j * C_];
    bf16* hb = h + (size_t)b * N_ * C_ + c;
    for (int i0 = 0; i0 < N_; i0 += 8){
        float acc[8] = {0.f,0.f,0.f,0.f,0.f,0.f,0.f,0.f};
        #pragma unroll
        for (int j = 0; j < N_; j++){
            float xv = xr[j];
            #pragma unroll
            for (int q = 0; q < 8; q++) acc[q] += adj[(i0 + q) * N_ + j] * xv;
        }
        #pragma unroll
        for (int q = 0; q < 8; q++)
            hb[(size_t)(i0 + q) * C_] = __float2bfloat16(leaky(acc[q]));
    }
}

// ---------------- K3/K13: bf16 MFMA GEMM, Out = epi(A @ W [+Res]) ------------
// A: [M][1024] bf16 row-major; WT: [1024][1024] bf16, WT[n][k] = W[k][n].
// 128x128 tile, BK=32, 4 waves, global_load_lds staging (m97 structure).
// EPI 0: Out = Res + A@W ; EPI 1: Out = leaky(A@W)
template<int EPI>
__global__ __launch_bounds__(256) void k_gemm_mfma(const bf16* __restrict__ Abf,
                                                   const bf16* __restrict__ WT,
                                                   const float* __restrict__ Res,
                                                   float* __restrict__ Out){
    __shared__ alignas(16) bf16 As[128 * 32];
    __shared__ alignas(16) bf16 Bs[128 * 32];
    const int K = 1024;
    int tid = threadIdx.x;
    int wave = tid >> 6, lane = tid & 63;
    int row0 = blockIdx.y * 128;   // M
    int col0 = blockIdx.x * 128;   // N

    // staging: thread t fills LDS bytes [t*16, t*16+16) => row t/4, col (t&3)*8
    const bf16* gA = Abf + (size_t)(row0 + (tid >> 2)) * K + (tid & 3) * 8;
    const bf16* gB = WT  + (size_t)(col0 + (tid >> 2)) * K + (tid & 3) * 8;
    bf16* dA0 = As + wave * 512;
    bf16* dA1 = As + 2048 + wave * 512;
    bf16* dB0 = Bs + wave * 512;
    bf16* dB1 = Bs + 2048 + wave * 512;

    // fragment read bases
    int wr = (wave >> 1) * 64, wc = (wave & 1) * 64;
    const bf16* rA = As + (wr + (lane & 15)) * 32 + (lane >> 4) * 8;
    const bf16* rB = Bs + (wc + (lane & 15)) * 32 + (lane >> 4) * 8;

    f32x4 acc[4][4];
    #pragma unroll
    for (int i = 0; i < 4; i++)
        #pragma unroll
        for (int j = 0; j < 4; j++) acc[i][j] = (f32x4){0.f, 0.f, 0.f, 0.f};

    for (int k0 = 0; k0 < K; k0 += 32){
        gll16(gA + k0, dA0);
        gll16(gA + (size_t)64 * K + k0, dA1);
        gll16(gB + k0, dB0);
        gll16(gB + (size_t)64 * K + k0, dB1);
        __syncthreads();                       // drains vmcnt -> staging visible
        bf16x8 a[4], b[4];
        #pragma unroll
        for (int i = 0; i < 4; i++) a[i] = *(const bf16x8*)(rA + i * 512);
        #pragma unroll
        for (int j = 0; j < 4; j++) b[j] = *(const bf16x8*)(rB + j * 512);
        #pragma unroll
        for (int i = 0; i < 4; i++)
            #pragma unroll
            for (int j = 0; j < 4; j++)
                acc[i][j] = __builtin_amdgcn_mfma_f32_16x16x32_bf16(a[i], b[j], acc[i][j], 0, 0, 0);
        __syncthreads();                       // all reads done before next stage
    }

    // D layout: row = (lane>>4)*4 + reg, col = lane&15 (per 16x16 fragment)
    int orow = row0 + wr + (lane >> 4) * 4;
    int ocol = col0 + wc + (lane & 15);
    #pragma unroll
    for (int i = 0; i < 4; i++){
        #pragma unroll
        for (int r = 0; r < 4; r++){
            int rr = orow + i * 16 + r;
            #pragma unroll
            for (int j = 0; j < 4; j++){
                size_t o = (size_t)rr * 1024 + ocol + j * 16;
                float v = acc[i][j][r];
                if (EPI == 0) v += Res[o];
                else          v = leaky(v);
                Out[o] = v;
            }
        }
    }
}

// ---------------- K5: Out = A @ W^T + bias (small, fp32) ----------------
#define PAD 68
__global__ __launch_bounds__(256) void k_gemm_bt_bias(const float* __restrict__ Am,
                                                      const float* __restrict__ W,
                                                      const float* __restrict__ bias,
                                                      float* __restrict__ Out, int M){
    __shared__ float As[16][PAD];
    __shared__ float Bs[16][PAD];
    int tid = threadIdx.x;
    int tx = tid & 15, ty = tid >> 4;
    int row0 = blockIdx.y * 64, col0 = blockIdx.x * 64;
    float acc[4][4] = {};
    int lr = tid >> 2;
    int lk = (tid & 3) * 4;
    for (int k0 = 0; k0 < C_; k0 += 16){
        float4 av = *(const float4*)(Am + (size_t)(row0 + lr) * C_ + k0 + lk);
        float4 wv = *(const float4*)(W  + (size_t)(col0 + lr) * C_ + k0 + lk);
        As[lk + 0][lr] = av.x; As[lk + 1][lr] = av.y;
        As[lk + 2][lr] = av.z; As[lk + 3][lr] = av.w;
        Bs[lk + 0][lr] = wv.x; Bs[lk + 1][lr] = wv.y;
        Bs[lk + 2][lr] = wv.z; Bs[lk + 3][lr] = wv.w;
        __syncthreads();
        #pragma unroll
        for (int kk = 0; kk < 16; kk++){
            float4 a  = *(const float4*)&As[kk][ty * 4];
            float4 bb = *(const float4*)&Bs[kk][tx * 4];
            float ar[4] = {a.x, a.y, a.z, a.w};
            float br[4] = {bb.x, bb.y, bb.z, bb.w};
            #pragma unroll
            for (int i = 0; i < 4; i++)
                #pragma unroll
                for (int j = 0; j < 4; j++) acc[i][j] += ar[i] * br[j];
        }
        __syncthreads();
    }
    for (int i = 0; i < 4; i++){
        int r = row0 + ty * 4 + i;
        for (int j = 0; j < 4; j++){
            int cl = col0 + tx * 4 + j;
            Out[(size_t)r * C_ + cl] = acc[i][j] + bias[cl];
        }
    }
}

// ---------------- K4: glb0[b,c] = mean_n x2[b,n,c] ----------------
__global__ void k_pool(const float* __restrict__ x2, float* __restrict__ glb0){
    int b = blockIdx.x, c = blockIdx.y * 256 + threadIdx.x;
    const float* p = x2 + (size_t)b * N_ * C_ + c;
    float s = 0.f;
    for (int nn = 0; nn < N_; nn++) s += p[nn * C_];
    glb0[b * C_ + c] = s * (1.f / N_);
}

// ---------------- K6: BN stats over batch ----------------
__global__ void k_bnstat(const float* __restrict__ g, float* __restrict__ mu,
                         float* __restrict__ rstd){
    int c = blockIdx.x * 256 + threadIdx.x;
    float s = 0.f, s2 = 0.f;
    for (int b = 0; b < B_; b++){ float v = g[b * C_ + c]; s += v; s2 += v * v; }
    float m = s * (1.f / B_);
    float var = s2 * (1.f / B_) - m * m;
    mu[c] = m;
    rstd[c] = rsqrtf(var + 1e-5f);
}

// ---------------- K7: glb2 = leaky(BN(glb1)) ----------------
__global__ void k_bnapply(const float* __restrict__ g, const float* __restrict__ mu,
                          const float* __restrict__ rstd, const float* __restrict__ gamma,
                          const float* __restrict__ beta, float* __restrict__ o){
    int i = blockIdx.x * 256 + threadIdx.x;
    int c = i & (C_ - 1);
    float v = (g[i] - mu[c]) * rstd[c] * gamma[c] + beta[c];
    o[i] = leaky(v);
}

// ---------------- K8: g1[b,n] = W1[n]·glb2[b] + ccb[n] ----------------
__global__ __launch_bounds__(256) void k_g1(const float* __restrict__ glb2,
                                            const float* __restrict__ ccw,
                                            const float* __restrict__ ccb,
                                            float* __restrict__ g1){
    __shared__ float gs[C_];
    int b = blockIdx.x, tid = threadIdx.x;
    for (int i = tid; i < C_; i += 256) gs[i] = glb2[b * C_ + i];
    __syncthreads();
    int w = tid >> 6, lane = tid & 63;
    for (int n = w; n < N_; n += 4){
        const float* wr = ccw + (size_t)n * (2 * C_);
        float acc = 0.f;
        for (int c = lane; c < C_; c += 64) acc += gs[c] * wr[c];
        for (int off = 32; off; off >>= 1) acc += __shfl_down(acc, off);
        if (lane == 0) g1[b * N_ + n] = acc + ccb[n];
    }
}

// ---------------- K9: dyn[b,n,m] = sigmoid(g1[b,n] + W2[n]·x2[b,m]) -------
__global__ __launch_bounds__(256) void k_dyn(const float* __restrict__ x2,
                                             const float* __restrict__ ccw,
                                             const float* __restrict__ g1,
                                             float* __restrict__ dyn){
    __shared__ float Ws[N_][33];
    __shared__ float Xs[N_][33];
    int b = blockIdx.x, tid = threadIdx.x;
    int tx = tid & 15, ty = tid >> 4;
    float acc[5][5] = {};
    const float* xb = x2 + (size_t)b * N_ * C_;
    for (int k0 = 0; k0 < C_; k0 += 32){
        for (int idx = tid; idx < N_ * 32; idx += 256){
            int n = idx >> 5, kk = idx & 31;
            Ws[n][kk] = ccw[(size_t)n * (2 * C_) + C_ + k0 + kk];
            Xs[n][kk] = xb[(size_t)n * C_ + k0 + kk];
        }
        __syncthreads();
        #pragma unroll 8
        for (int kk = 0; kk < 32; kk++){
            float a[5], bb[5];
            #pragma unroll
            for (int i = 0; i < 5; i++) a[i] = Ws[ty * 5 + i][kk];
            #pragma unroll
            for (int j = 0; j < 5; j++) bb[j] = Xs[tx * 5 + j][kk];
            #pragma unroll
            for (int i = 0; i < 5; i++)
                #pragma unroll
                for (int j = 0; j < 5; j++) acc[i][j] += a[i] * bb[j];
        }
        __syncthreads();
    }
    for (int i = 0; i < 5; i++){
        int n = ty * 5 + i;
        float gg = g1[b * N_ + n];
        for (int j = 0; j < 5; j++){
            int m = tx * 5 + j;
            dyn[(size_t)b * N_ * N_ + n * N_ + m] = sigmoidf_(acc[i][j] + gg);
        }
    }
}

// ---------------- K10: loss rows + dinv ----------------
__global__ __launch_bounds__(128) void k_lossrow(const float* __restrict__ out1,
                                                 const float* __restrict__ dyn,
                                                 float* __restrict__ dinv,
                                                 float* __restrict__ lossp){
    __shared__ float o1s[N_];
    __shared__ float dd[N_];
    int b = blockIdx.x, t = threadIdx.x;
    if (t < N_) o1s[t] = sigmoidf_(out1[b * N_ + t]);
    __syncthreads();
    const float* db = dyn + (size_t)b * N_ * N_;
    if (t < N_){
        float acc = 0.f;
        for (int nn = 0; nn < N_; nn++) acc += o1s[nn] * db[nn * N_ + t];
        float tt = acc * (1.f / N_);
        float diff = o1s[t] - tt;
        dd[t] = diff * diff;
        float rs = 0.f;
        for (int m = 0; m < N_; m++) rs += db[t * N_ + m];
        dinv[b * N_ + t] = rsqrtf(rs);
    }
    __syncthreads();
    if (t == 0){
        float s = 0.f;
        for (int m = 0; m < N_; m++) s += dd[m];
        lossp[b] = sqrtf(s);
    }
}

// ---------------- K11: loss = sum(lossp) ----------------
__global__ void k_lsum(const float* __restrict__ lossp, float* __restrict__ out_loss){
    float v = lossp[threadIdx.x];
    for (int off = 32; off; off >>= 1) v += __shfl_down(v, off);
    __shared__ float wsum[4];
    int lane = threadIdx.x & 63, w = threadIdx.x >> 6;
    if (lane == 0) wsum[w] = v;
    __syncthreads();
    if (threadIdx.x == 0) out_loss[0] = wsum[0] + wsum[1] + wsum[2] + wsum[3];
}

// ---------------- K12: h2 = bf16(leaky(adjs @ x2)), register-resident --------
__global__ __launch_bounds__(256) void k_prop_dyn(const float* __restrict__ x2,
                                                  const float* __restrict__ dyn,
                                                  const float* __restrict__ dinv,
                                                  bf16* __restrict__ h){
    int b = blockIdx.x, c = blockIdx.y * 256 + threadIdx.x;
    const float* xb = x2 + (size_t)b * N_ * C_ + c;
    const float* db = dyn + (size_t)b * N_ * N_;
    const float* di = dinv + (size_t)b * N_;
    float xr[N_];
    #pragma unroll
    for (int j = 0; j < N_; j++) xr[j] = xb[(size_t)j * C_] * di[j];
    bf16* hb = h + (size_t)b * N_ * C_ + c;
    for (int i0 = 0; i0 < N_; i0 += 8){
        float acc[8] = {0.f,0.f,0.f,0.f,0.f,0.f,0.f,0.f};
        #pragma unroll
        for (int j = 0; j < N_; j++){
            float xv = xr[j];
            #pragma unroll
            for (int q = 0; q < 8; q++) acc[q] += db[j * N_ + (i0 + q)] * xv;
        }
        #pragma unroll
        for (int q = 0; q < 8; q++)
            hb[(size_t)(i0 + q) * C_] = __float2bfloat16(leaky(di[i0 + q] * acc[q]));
    }
}

extern "C" void kernel_launch(void* const* d_in, const int* in_sizes, int n_in,
                              void* d_out, int out_size, void* d_ws, size_t ws_size,
                              hipStream_t stream) {
    const float* x     = (const float*)d_in[0];
    const float* out1  = (const float*)d_in[1];
    const float* A     = (const float*)d_in[2];
    const float* sw    = (const float*)d_in[3];
    const float* cgw   = (const float*)d_in[4];
    const float* cgb   = (const float*)d_in[5];
    const float* gamma = (const float*)d_in[6];
    const float* beta  = (const float*)d_in[7];
    const float* ccw   = (const float*)d_in[8];
    const float* ccb   = (const float*)d_in[9];
    const float* dw    = (const float*)d_in[10];
    float* out = (float*)d_out;

    const size_t XN = (size_t)B_ * N_ * C_;   // 20,971,520
    char* p = (char*)d_ws;
    float* X2   = (float*)p;  p += XN * 4;               // 84 MB
    bf16*  Hbf  = (bf16*)p;   p += XN * 2;               // 42 MB (h1 then h2)
    bf16*  SWT  = (bf16*)p;   p += (size_t)C_ * C_ * 2;  // 2 MB
    bf16*  DWT  = (bf16*)p;   p += (size_t)C_ * CO_ * 2; // 2 MB
    float* ADJ  = (float*)p;  p += N_ * N_ * 4;
    float* GLB0 = (float*)p;  p += (size_t)B_ * C_ * 4;
    float* GLB1 = (float*)p;  p += (size_t)B_ * C_ * 4;
    float* GLB2 = (float*)p;  p += (size_t)B_ * C_ * 4;
    float* MU   = (float*)p;  p += C_ * 4;
    float* RSTD = (float*)p;  p += C_ * 4;
    float* G1   = (float*)p;  p += (size_t)B_ * N_ * 4;
    float* DYN  = (float*)p;  p += (size_t)B_ * N_ * N_ * 4;
    float* DINV = (float*)p;  p += (size_t)B_ * N_ * 4;
    float* LOSSP= (float*)p;  p += B_ * 4;

    const int M = B_ * N_;                     // 20480

    k_convT<<<dim3(32, 32), 256, 0, stream>>>(sw, SWT);
    k_convT<<<dim3(32, 32), 256, 0, stream>>>(dw, DWT);
    k_adj<<<1, 128, 0, stream>>>(A, ADJ);
    k_prop_static<<<dim3(B_, C_ / 256), 256, 0, stream>>>(x, ADJ, Hbf);
    k_gemm_mfma<0><<<dim3(C_ / 128, M / 128), 256, 0, stream>>>(Hbf, SWT, x, X2);
    k_pool<<<dim3(B_, C_ / 256), 256, 0, stream>>>(X2, GLB0);
    k_gemm_bt_bias<<<dim3(C_ / 64, B_ / 64), 256, 0, stream>>>(GLB0, cgw, cgb, GLB1, B_);
    k_bnstat<<<C_ / 256, 256, 0, stream>>>(GLB1, MU, RSTD);
    k_bnapply<<<(B_ * C_) / 256, 256, 0, stream>>>(GLB1, MU, RSTD, gamma, beta, GLB2);
    k_g1<<<B_, 256, 0, stream>>>(GLB2, ccw, ccb, G1);
    k_dyn<<<B_, 256, 0, stream>>>(X2, ccw, G1, DYN);
    k_lossrow<<<B_, 128, 0, stream>>>(out1, DYN, DINV, LOSSP);
    k_lsum<<<1, 256, 0, stream>>>(LOSSP, out + (size_t)B_ * N_ * CO_);
    k_prop_dyn<<<dim3(B_, C_ / 256), 256, 0, stream>>>(X2, DYN, DINV, Hbf);
    k_gemm_mfma<1><<<dim3(CO_ / 128, M / 128), 256, 0, stream>>>(Hbf, DWT, nullptr, out);
}

// Round 3
// 419.895 us; speedup vs baseline: 5.4464x; 3.1258x over previous
//
#include <hip/hip_runtime.h>
#include <hip/hip_bf16.h>
#include <math.h>

#define B_  256
#define N_  80
#define C_  1024
#define CO_ 1024

typedef __hip_bfloat16 bf16;
using bf16x8 = __attribute__((ext_vector_type(8))) short;   // 8 bf16 = 4 VGPRs
using f32x4  = __attribute__((ext_vector_type(4))) float;

__device__ __forceinline__ float leaky(float v){ return v >= 0.f ? v : 0.2f * v; }
__device__ __forceinline__ float sigmoidf_(float v){ return 1.f / (1.f + __expf(-v)); }

__device__ __forceinline__ void gll16(const void* g, void* l){
    __builtin_amdgcn_global_load_lds(
        (const __attribute__((address_space(1))) void*)g,
        (__attribute__((address_space(3))) void*)l, 16, 0, 0);
}

// ---------------- K0: transpose + convert weight: WT[n][k] = bf16(W[k][n]) ----
__global__ __launch_bounds__(256) void k_convT(const float* __restrict__ W, bf16* __restrict__ WT){
    __shared__ float t[32][33];
    int k0 = blockIdx.y * 32, n0 = blockIdx.x * 32;
    int tx = threadIdx.x & 31, ty = threadIdx.x >> 5;
    for (int i = ty; i < 32; i += 8) t[i][tx] = W[(size_t)(k0 + i) * 1024 + n0 + tx];
    __syncthreads();
    for (int i = ty; i < 32; i += 8)
        WT[(size_t)(n0 + i) * 1024 + k0 + tx] = __float2bfloat16(t[tx][i]);
}

// ---------------- K0b: W2b[n][k] = bf16(ccw[n][1024+k]) ----------------
__global__ void k_cvt_w2(const float* __restrict__ ccw, bf16* __restrict__ W2b){
    int i = blockIdx.x * 256 + threadIdx.x;   // 80*1024 total
    W2b[i] = __float2bfloat16(ccw[((size_t)(i >> 10) << 11) + 1024 + (i & 1023)]);
}

// ---------------- K1: adj_s (bf16, [80][88] padded rows) ----------------
__global__ void k_adj(const float* __restrict__ A, bf16* __restrict__ adjb){
    __shared__ float d[N_];
    int t = threadIdx.x;
    if (t < N_){
        float s = 0.f;
        for (int j = 0; j < N_; j++) s += A[t * N_ + j];
        d[t] = rsqrtf(s);
    }
    __syncthreads();
    for (int idx = t; idx < N_ * N_; idx += 256){
        int i = idx / N_, j = idx - i * N_;
        adjb[i * 88 + j] = __float2bfloat16(d[i] * A[j * N_ + i] * d[j]);
    }
}

// ---------------- K2/K12: h = bf16(leaky(A[80x80] @ X[80x1024])) via MFMA ----
// MODE 0: X = x (fp32), A = static adj.  MODE 1: X = X2b (bf16), A = ADJD[b].
// grid (B, 4): one b, 256 output cols per block. 4 waves, each 64 cols x 80 rows.
template<int MODE>
__global__ __launch_bounds__(256) void k_prop_mfma(const void* __restrict__ srcv,
                                                   const bf16* __restrict__ Ag_,
                                                   bf16* __restrict__ H){
    __shared__ bf16 Btl[256 * 88];   // x-tile transposed: Btl[c][m], rows 88 (176B, 2-way free)
    __shared__ bf16 Al [80 * 88];    // A[n][m]
    int b = blockIdx.x, c0 = blockIdx.y * 256, tid = threadIdx.x;
    int wave = tid >> 6, lane = tid & 63;
    int l15 = lane & 15, hi = lane >> 4;

    // A panel copy: 80*88*2 = 14080 B = 880 chunks of 16B, flat gll16
    const bf16* Ag = Ag_ + (MODE ? (size_t)b * 80 * 88 : 0);
    #pragma unroll
    for (int k = 0; k < 4; k++){
        int cb = wave * 64 + 256 * k;            // wave-uniform chunk base
        if (cb + lane < 880)
            gll16(Ag + (size_t)(cb + lane) * 8, Al + (size_t)cb * 8);
    }

    // B staging: thread tid owns column c = c0+tid; transpose rows m -> Btl[tid][m]
    {
        size_t rowbase = (size_t)b * 80 * 1024 + c0 + tid;
        #pragma unroll 8
        for (int m = 0; m < 80; m++){
            bf16 h;
            if (MODE == 0) h = __float2bfloat16(((const float*)srcv)[rowbase + (size_t)m * 1024]);
            else           h = ((const bf16*)srcv)[rowbase + (size_t)m * 1024];
            Btl[tid * 88 + m] = h;
        }
    }
    __syncthreads();

    f32x4 acc[5][4];
    #pragma unroll
    for (int i = 0; i < 5; i++)
        #pragma unroll
        for (int j = 0; j < 4; j++) acc[i][j] = (f32x4){0.f, 0.f, 0.f, 0.f};

    #pragma unroll
    for (int ks = 0; ks < 3; ks++){
        bf16x8 a[5], bv[4];
        if (ks < 2){
            int k0 = ks * 32;
            #pragma unroll
            for (int i = 0; i < 5; i++)
                a[i] = *(const bf16x8*)(Al + (i * 16 + l15) * 88 + k0 + hi * 8);
            #pragma unroll
            for (int j = 0; j < 4; j++)
                bv[j] = *(const bf16x8*)(Btl + (wave * 64 + j * 16 + l15) * 88 + k0 + hi * 8);
        } else {
            // K tail 64..79: lane-groups 0,1 carry real data; groups 2,3 contribute zeros
            int koff = (hi < 2) ? 64 + hi * 8 : 0;
            #pragma unroll
            for (int i = 0; i < 5; i++){
                bf16x8 v = *(const bf16x8*)(Al + (i * 16 + l15) * 88 + koff);
                if (hi >= 2) v = 0;
                a[i] = v;
            }
            #pragma unroll
            for (int j = 0; j < 4; j++){
                bf16x8 v = *(const bf16x8*)(Btl + (wave * 64 + j * 16 + l15) * 88 + koff);
                if (hi >= 2) v = 0;
                bv[j] = v;
            }
        }
        #pragma unroll
        for (int i = 0; i < 5; i++)
            #pragma unroll
            for (int j = 0; j < 4; j++)
                acc[i][j] = __builtin_amdgcn_mfma_f32_16x16x32_bf16(a[i], bv[j], acc[i][j], 0, 0, 0);
    }

    // D: row = hi*4 + r (+16i), col = l15 (+16j)
    #pragma unroll
    for (int i = 0; i < 5; i++){
        #pragma unroll
        for (int r = 0; r < 4; r++){
            int orow = i * 16 + hi * 4 + r;
            #pragma unroll
            for (int j = 0; j < 4; j++){
                int ocol = c0 + wave * 64 + j * 16 + l15;
                H[(size_t)b * 81920 + (size_t)orow * 1024 + ocol] =
                    __float2bfloat16(leaky(acc[i][j][r]));
            }
        }
    }
}

// ---------------- K3/K13: bf16 MFMA GEMM, Out = epi(A @ W [+Res]) ------------
// EPI 0: Outb = bf16(A@W + Res) ; EPI 1: Outf = leaky(A@W)
template<int EPI>
__global__ __launch_bounds__(256) void k_gemm_mfma(const bf16* __restrict__ Abf,
                                                   const bf16* __restrict__ WT,
                                                   const float* __restrict__ Res,
                                                   void* __restrict__ Outv){
    __shared__ alignas(16) bf16 As[128 * 32];
    __shared__ alignas(16) bf16 Bs[128 * 32];
    const int K = 1024;
    int tid = threadIdx.x;
    int wave = tid >> 6, lane = tid & 63;
    int row0 = blockIdx.y * 128;
    int col0 = blockIdx.x * 128;

    const bf16* gA = Abf + (size_t)(row0 + (tid >> 2)) * K + (tid & 3) * 8;
    const bf16* gB = WT  + (size_t)(col0 + (tid >> 2)) * K + (tid & 3) * 8;
    bf16* dA0 = As + wave * 512;
    bf16* dA1 = As + 2048 + wave * 512;
    bf16* dB0 = Bs + wave * 512;
    bf16* dB1 = Bs + 2048 + wave * 512;

    int wr = (wave >> 1) * 64, wc = (wave & 1) * 64;
    const bf16* rA = As + (wr + (lane & 15)) * 32 + (lane >> 4) * 8;
    const bf16* rB = Bs + (wc + (lane & 15)) * 32 + (lane >> 4) * 8;

    f32x4 acc[4][4];
    #pragma unroll
    for (int i = 0; i < 4; i++)
        #pragma unroll
        for (int j = 0; j < 4; j++) acc[i][j] = (f32x4){0.f, 0.f, 0.f, 0.f};

    for (int k0 = 0; k0 < K; k0 += 32){
        gll16(gA + k0, dA0);
        gll16(gA + (size_t)64 * K + k0, dA1);
        gll16(gB + k0, dB0);
        gll16(gB + (size_t)64 * K + k0, dB1);
        __syncthreads();
        bf16x8 a[4], b[4];
        #pragma unroll
        for (int i = 0; i < 4; i++) a[i] = *(const bf16x8*)(rA + i * 512);
        #pragma unroll
        for (int j = 0; j < 4; j++) b[j] = *(const bf16x8*)(rB + j * 512);
        #pragma unroll
        for (int i = 0; i < 4; i++)
            #pragma unroll
            for (int j = 0; j < 4; j++)
                acc[i][j] = __builtin_amdgcn_mfma_f32_16x16x32_bf16(a[i], b[j], acc[i][j], 0, 0, 0);
        __syncthreads();
    }

    int orow = row0 + wr + (lane >> 4) * 4;
    int ocol = col0 + wc + (lane & 15);
    #pragma unroll
    for (int i = 0; i < 4; i++){
        #pragma unroll
        for (int r = 0; r < 4; r++){
            int rr = orow + i * 16 + r;
            #pragma unroll
            for (int j = 0; j < 4; j++){
                size_t o = (size_t)rr * 1024 + ocol + j * 16;
                float v = acc[i][j][r];
                if (EPI == 0) ((bf16*)Outv)[o] = __float2bfloat16(v + Res[o]);
                else          ((float*)Outv)[o] = leaky(v);
            }
        }
    }
}

// ---------------- K5: Out = A @ W^T + bias (small, fp32) ----------------
#define PAD 68
__global__ __launch_bounds__(256) void k_gemm_bt_bias(const float* __restrict__ Am,
                                                      const float* __restrict__ W,
                                                      const float* __restrict__ bias,
                                                      float* __restrict__ Out, int M){
    __shared__ float As[16][PAD];
    __shared__ float Bs[16][PAD];
    int tid = threadIdx.x;
    int tx = tid & 15, ty = tid >> 4;
    int row0 = blockIdx.y * 64, col0 = blockIdx.x * 64;
    float acc[4][4] = {};
    int lr = tid >> 2;
    int lk = (tid & 3) * 4;
    for (int k0 = 0; k0 < C_; k0 += 16){
        float4 av = *(const float4*)(Am + (size_t)(row0 + lr) * C_ + k0 + lk);
        float4 wv = *(const float4*)(W  + (size_t)(col0 + lr) * C_ + k0 + lk);
        As[lk + 0][lr] = av.x; As[lk + 1][lr] = av.y;
        As[lk + 2][lr] = av.z; As[lk + 3][lr] = av.w;
        Bs[lk + 0][lr] = wv.x; Bs[lk + 1][lr] = wv.y;
        Bs[lk + 2][lr] = wv.z; Bs[lk + 3][lr] = wv.w;
        __syncthreads();
        #pragma unroll
        for (int kk = 0; kk < 16; kk++){
            float4 a  = *(const float4*)&As[kk][ty * 4];
            float4 bb = *(const float4*)&Bs[kk][tx * 4];
            float ar[4] = {a.x, a.y, a.z, a.w};
            float br[4] = {bb.x, bb.y, bb.z, bb.w};
            #pragma unroll
            for (int i = 0; i < 4; i++)
                #pragma unroll
                for (int j = 0; j < 4; j++) acc[i][j] += ar[i] * br[j];
        }
        __syncthreads();
    }
    for (int i = 0; i < 4; i++){
        int r = row0 + ty * 4 + i;
        for (int j = 0; j < 4; j++){
            int cl = col0 + tx * 4 + j;
            Out[(size_t)r * C_ + cl] = acc[i][j] + bias[cl];
        }
    }
}

// ---------------- K4: glb0[b,c] = mean_n x2b[b,n,c] ----------------
__global__ void k_pool(const bf16* __restrict__ X2b, float* __restrict__ glb0){
    int b = blockIdx.x, c = blockIdx.y * 256 + threadIdx.x;
    const bf16* p = X2b + (size_t)b * 81920 + c;
    float s = 0.f;
    for (int nn = 0; nn < N_; nn++) s += __bfloat162float(p[nn * 1024]);
    glb0[b * C_ + c] = s * (1.f / N_);
}

// ---------------- K6: BN stats over batch ----------------
__global__ void k_bnstat(const float* __restrict__ g, float* __restrict__ mu,
                         float* __restrict__ rstd){
    int c = blockIdx.x * 256 + threadIdx.x;
    float s = 0.f, s2 = 0.f;
    for (int b = 0; b < B_; b++){ float v = g[b * C_ + c]; s += v; s2 += v * v; }
    float m = s * (1.f / B_);
    float var = s2 * (1.f / B_) - m * m;
    mu[c] = m;
    rstd[c] = rsqrtf(var + 1e-5f);
}

// ---------------- K7: glb2 = leaky(BN(glb1)) ----------------
__global__ void k_bnapply(const float* __restrict__ g, const float* __restrict__ mu,
                          const float* __restrict__ rstd, const float* __restrict__ gamma,
                          const float* __restrict__ beta, float* __restrict__ o){
    int i = blockIdx.x * 256 + threadIdx.x;
    int c = i & (C_ - 1);
    float v = (g[i] - mu[c]) * rstd[c] * gamma[c] + beta[c];
    o[i] = leaky(v);
}

// ---------------- K8: g1[b,n] = W1[n]·glb2[b] + ccb[n] ----------------
__global__ __launch_bounds__(256) void k_g1(const float* __restrict__ glb2,
                                            const float* __restrict__ ccw,
                                            const float* __restrict__ ccb,
                                            float* __restrict__ g1){
    __shared__ float gs[C_];
    int b = blockIdx.x, tid = threadIdx.x;
    for (int i = tid; i < C_; i += 256) gs[i] = glb2[b * C_ + i];
    __syncthreads();
    int w = tid >> 6, lane = tid & 63;
    for (int n = w; n < N_; n += 4){
        const float* wr = ccw + (size_t)n * (2 * C_);
        float acc = 0.f;
        for (int c = lane; c < C_; c += 64) acc += gs[c] * wr[c];
        for (int off = 32; off; off >>= 1) acc += __shfl_down(acc, off);
        if (lane == 0) g1[b * N_ + n] = acc + ccb[n];
    }
}

// ---------------- K9: dyn = sigmoid(W2b @ X2b[b]^T + g1)  (MFMA dual form) ---
// 5 waves; wave w owns output rows 16w..16w+15, all 80 cols.
__global__ __launch_bounds__(320) void k_dyn_mfma(const bf16* __restrict__ X2b,
                                                  const bf16* __restrict__ W2b,
                                                  const float* __restrict__ G1,
                                                  float* __restrict__ dyn){
    __shared__ alignas(16) bf16 At[80 * 32];
    __shared__ alignas(16) bf16 Bt[80 * 32];
    int b = blockIdx.x, tid = threadIdx.x;
    int wave = tid >> 6, lane = tid & 63;
    int l15 = lane & 15, hi = lane >> 4;

    const bf16* gA = W2b + (size_t)(wave * 16 + (lane >> 2)) * 1024 + (lane & 3) * 8;
    const bf16* gB = X2b + ((size_t)b * 80 + wave * 16 + (lane >> 2)) * 1024 + (lane & 3) * 8;
    bf16* dA = At + wave * 512;
    bf16* dB = Bt + wave * 512;

    f32x4 acc[5];
    #pragma unroll
    for (int j = 0; j < 5; j++) acc[j] = (f32x4){0.f, 0.f, 0.f, 0.f};

    for (int k0 = 0; k0 < 1024; k0 += 32){
        gll16(gA + k0, dA);
        gll16(gB + k0, dB);
        __syncthreads();
        bf16x8 a = *(const bf16x8*)(At + (wave * 16 + l15) * 32 + hi * 8);
        bf16x8 bv[5];
        #pragma unroll
        for (int j = 0; j < 5; j++)
            bv[j] = *(const bf16x8*)(Bt + (j * 16 + l15) * 32 + hi * 8);
        #pragma unroll
        for (int j = 0; j < 5; j++)
            acc[j] = __builtin_amdgcn_mfma_f32_16x16x32_bf16(a, bv[j], acc[j], 0, 0, 0);
        __syncthreads();
    }

    #pragma unroll
    for (int r = 0; r < 4; r++){
        int n = wave * 16 + hi * 4 + r;
        float g = G1[b * N_ + n];
        #pragma unroll
        for (int j = 0; j < 5; j++){
            int m = j * 16 + l15;
            dyn[(size_t)b * 6400 + n * N_ + m] = sigmoidf_(acc[j][r] + g);
        }
    }
}

// ---------------- K10: loss rows + dinv ----------------
__global__ __launch_bounds__(128) void k_lossrow(const float* __restrict__ out1,
                                                 const float* __restrict__ dyn,
                                                 float* __restrict__ dinv,
                                                 float* __restrict__ lossp){
    __shared__ float o1s[N_];
    __shared__ float dd[N_];
    int b = blockIdx.x, t = threadIdx.x;
    if (t < N_) o1s[t] = sigmoidf_(out1[b * N_ + t]);
    __syncthreads();
    const float* db = dyn + (size_t)b * N_ * N_;
    if (t < N_){
        float acc = 0.f;
        for (int nn = 0; nn < N_; nn++) acc += o1s[nn] * db[nn * N_ + t];
        float tt = acc * (1.f / N_);
        float diff = o1s[t] - tt;
        dd[t] = diff * diff;
        float rs = 0.f;
        for (int m = 0; m < N_; m++) rs += db[t * N_ + m];
        dinv[b * N_ + t] = rsqrtf(rs);
    }
    __syncthreads();
    if (t == 0){
        float s = 0.f;
        for (int m = 0; m < N_; m++) s += dd[m];
        lossp[b] = sqrtf(s);
    }
}

// ---------------- K11: loss = sum(lossp) ----------------
__global__ void k_lsum(const float* __restrict__ lossp, float* __restrict__ out_loss){
    float v = lossp[threadIdx.x];
    for (int off = 32; off; off >>= 1) v += __shfl_down(v, off);
    __shared__ float wsum[4];
    int lane = threadIdx.x & 63, w = threadIdx.x >> 6;
    if (lane == 0) wsum[w] = v;
    __syncthreads();
    if (threadIdx.x == 0) out_loss[0] = wsum[0] + wsum[1] + wsum[2] + wsum[3];
}

// ---------------- K12a: ADJD[b][n][m] = bf16(di[n]*dyn[b][m][n]*di[m]) -------
__global__ void k_adjs_d(const float* __restrict__ dyn, const float* __restrict__ dinv,
                         bf16* __restrict__ ADJD){
    __shared__ float di[N_];
    int b = blockIdx.x, tid = threadIdx.x;
    if (tid < N_) di[tid] = dinv[b * N_ + tid];
    __syncthreads();
    const float* db = dyn + (size_t)b * 6400;
    bf16* ab = ADJD + (size_t)b * 80 * 88;
    for (int idx = tid; idx < 6400; idx += 256){
        int n = idx / 80, m = idx - n * 80;
        ab[n * 88 + m] = __float2bfloat16(di[n] * db[m * 80 + n] * di[m]);
    }
}

extern "C" void kernel_launch(void* const* d_in, const int* in_sizes, int n_in,
                              void* d_out, int out_size, void* d_ws, size_t ws_size,
                              hipStream_t stream) {
    const float* x     = (const float*)d_in[0];
    const float* out1  = (const float*)d_in[1];
    const float* A     = (const float*)d_in[2];
    const float* sw    = (const float*)d_in[3];
    const float* cgw   = (const float*)d_in[4];
    const float* cgb   = (const float*)d_in[5];
    const float* gamma = (const float*)d_in[6];
    const float* beta  = (const float*)d_in[7];
    const float* ccw   = (const float*)d_in[8];
    const float* ccb   = (const float*)d_in[9];
    const float* dw    = (const float*)d_in[10];
    float* out = (float*)d_out;

    const size_t XN = (size_t)B_ * N_ * C_;   // 20,971,520
    char* p = (char*)d_ws;
    bf16*  Hbf  = (bf16*)p;   p += XN * 2;               // 42 MB
    bf16*  X2b  = (bf16*)p;   p += XN * 2;               // 42 MB
    bf16*  SWT  = (bf16*)p;   p += (size_t)C_ * C_ * 2;  // 2 MB
    bf16*  DWT  = (bf16*)p;   p += (size_t)C_ * CO_ * 2; // 2 MB
    bf16*  W2b  = (bf16*)p;   p += (size_t)N_ * C_ * 2;  // 160 KB
    bf16*  ADJS = (bf16*)p;   p += (size_t)80 * 88 * 2;
    bf16*  ADJD = (bf16*)p;   p += (size_t)B_ * 80 * 88 * 2;  // 3.6 MB
    float* GLB0 = (float*)p;  p += (size_t)B_ * C_ * 4;
    float* GLB1 = (float*)p;  p += (size_t)B_ * C_ * 4;
    float* GLB2 = (float*)p;  p += (size_t)B_ * C_ * 4;
    float* MU   = (float*)p;  p += C_ * 4;
    float* RSTD = (float*)p;  p += C_ * 4;
    float* G1   = (float*)p;  p += (size_t)B_ * N_ * 4;
    float* DYN  = (float*)p;  p += (size_t)B_ * N_ * N_ * 4;  // 6.55 MB
    float* DINV = (float*)p;  p += (size_t)B_ * N_ * 4;
    float* LOSSP= (float*)p;  p += B_ * 4;

    const int M = B_ * N_;                     // 20480

    k_convT<<<dim3(32, 32), 256, 0, stream>>>(sw, SWT);
    k_convT<<<dim3(32, 32), 256, 0, stream>>>(dw, DWT);
    k_cvt_w2<<<(N_ * C_) / 256, 256, 0, stream>>>(ccw, W2b);
    k_adj<<<1, 256, 0, stream>>>(A, ADJS);
    k_prop_mfma<0><<<dim3(B_, 4), 256, 0, stream>>>(x, ADJS, Hbf);
    k_gemm_mfma<0><<<dim3(C_ / 128, M / 128), 256, 0, stream>>>(Hbf, SWT, x, X2b);
    k_pool<<<dim3(B_, C_ / 256), 256, 0, stream>>>(X2b, GLB0);
    k_gemm_bt_bias<<<dim3(C_ / 64, B_ / 64), 256, 0, stream>>>(GLB0, cgw, cgb, GLB1, B_);
    k_bnstat<<<C_ / 256, 256, 0, stream>>>(GLB1, MU, RSTD);
    k_bnapply<<<(B_ * C_) / 256, 256, 0, stream>>>(GLB1, MU, RSTD, gamma, beta, GLB2);
    k_g1<<<B_, 256, 0, stream>>>(GLB2, ccw, ccb, G1);
    k_dyn_mfma<<<B_, 320, 0, stream>>>(X2b, W2b, G1, DYN);
    k_lossrow<<<B_, 128, 0, stream>>>(out1, DYN, DINV, LOSSP);
    k_lsum<<<1, 256, 0, stream>>>(LOSSP, out + (size_t)B_ * N_ * CO_);
    k_adjs_d<<<B_, 256, 0, stream>>>(DYN, DINV, ADJD);
    k_prop_mfma<1><<<dim3(B_, 4), 256, 0, stream>>>(X2b, ADJD, Hbf);
    k_gemm_mfma<1><<<dim3(CO_ / 128, M / 128), 256, 0, stream>>>(Hbf, DWT, nullptr, out);
}

// Round 4
// 332.465 us; speedup vs baseline: 6.8786x; 1.2630x over previous
//
#include <hip/hip_runtime.h>
#include <hip/hip_bf16.h>
#include <math.h>

#define B_  256
#define N_  80
#define C_  1024
#define CO_ 1024

typedef __hip_bfloat16 bf16;
using bf16x8 = __attribute__((ext_vector_type(8))) short;   // 8 bf16 = 4 VGPRs
using f32x4  = __attribute__((ext_vector_type(4))) float;

__device__ __forceinline__ float leaky(float v){ return v >= 0.f ? v : 0.2f * v; }
__device__ __forceinline__ float sigmoidf_(float v){ return 1.f / (1.f + __expf(-v)); }

__device__ __forceinline__ void gll16(const void* g, void* l){
    __builtin_amdgcn_global_load_lds(
        (const __attribute__((address_space(1))) void*)g,
        (__attribute__((address_space(3))) void*)l, 16, 0, 0);
}

// ---------------- K0: transpose + convert weight: WT[n][k] = bf16(W[k][n]) ----
__global__ __launch_bounds__(256) void k_convT(const float* __restrict__ W, bf16* __restrict__ WT){
    __shared__ float t[32][33];
    int k0 = blockIdx.y * 32, n0 = blockIdx.x * 32;
    int tx = threadIdx.x & 31, ty = threadIdx.x >> 5;
    for (int i = ty; i < 32; i += 8) t[i][tx] = W[(size_t)(k0 + i) * 1024 + n0 + tx];
    __syncthreads();
    for (int i = ty; i < 32; i += 8)
        WT[(size_t)(n0 + i) * 1024 + k0 + tx] = __float2bfloat16(t[tx][i]);
}

// ---------------- K0b: ccwb = bf16(ccw), [80][2048] ----------------
__global__ void k_cvt_ccw(const float* __restrict__ ccw, bf16* __restrict__ ccwb){
    int i = blockIdx.x * 256 + threadIdx.x;   // 80*2048 total
    ccwb[i] = __float2bfloat16(ccw[i]);
}

// ---------------- K1: adj_s (bf16, [80][88] padded rows) ----------------
__global__ void k_adj(const float* __restrict__ A, bf16* __restrict__ adjb){
    __shared__ float d[N_];
    int t = threadIdx.x;
    if (t < N_){
        float s = 0.f;
        for (int j = 0; j < N_; j++) s += A[t * N_ + j];
        d[t] = rsqrtf(s);
    }
    __syncthreads();
    for (int idx = t; idx < N_ * N_; idx += 256){
        int i = idx / N_, j = idx - i * N_;
        adjb[i * 88 + j] = __float2bfloat16(d[i] * A[j * N_ + i] * d[j]);
    }
}

// ---------------- K2/K12: h = bf16(leaky(A[80x80] @ X[80x1024])) via MFMA ----
// MODE 0: X = x (fp32), A = static adj.  MODE 1: X = X2b (bf16), A = ADJD[b].
template<int MODE>
__global__ __launch_bounds__(256) void k_prop_mfma(const void* __restrict__ srcv,
                                                   const bf16* __restrict__ Ag_,
                                                   bf16* __restrict__ H){
    __shared__ bf16 Btl[256 * 88];
    __shared__ bf16 Al [80 * 88];
    int b = blockIdx.x, c0 = blockIdx.y * 256, tid = threadIdx.x;
    int wave = tid >> 6, lane = tid & 63;
    int l15 = lane & 15, hi = lane >> 4;

    const bf16* Ag = Ag_ + (MODE ? (size_t)b * 80 * 88 : 0);
    #pragma unroll
    for (int k = 0; k < 4; k++){
        int cb = wave * 64 + 256 * k;
        if (cb + lane < 880)
            gll16(Ag + (size_t)(cb + lane) * 8, Al + (size_t)cb * 8);
    }
    {
        size_t rowbase = (size_t)b * 80 * 1024 + c0 + tid;
        #pragma unroll 8
        for (int m = 0; m < 80; m++){
            bf16 h;
            if (MODE == 0) h = __float2bfloat16(((const float*)srcv)[rowbase + (size_t)m * 1024]);
            else           h = ((const bf16*)srcv)[rowbase + (size_t)m * 1024];
            Btl[tid * 88 + m] = h;
        }
    }
    __syncthreads();

    f32x4 acc[5][4];
    #pragma unroll
    for (int i = 0; i < 5; i++)
        #pragma unroll
        for (int j = 0; j < 4; j++) acc[i][j] = (f32x4){0.f, 0.f, 0.f, 0.f};

    #pragma unroll
    for (int ks = 0; ks < 3; ks++){
        bf16x8 a[5], bv[4];
        if (ks < 2){
            int k0 = ks * 32;
            #pragma unroll
            for (int i = 0; i < 5; i++)
                a[i] = *(const bf16x8*)(Al + (i * 16 + l15) * 88 + k0 + hi * 8);
            #pragma unroll
            for (int j = 0; j < 4; j++)
                bv[j] = *(const bf16x8*)(Btl + (wave * 64 + j * 16 + l15) * 88 + k0 + hi * 8);
        } else {
            int koff = (hi < 2) ? 64 + hi * 8 : 0;
            #pragma unroll
            for (int i = 0; i < 5; i++){
                bf16x8 v = *(const bf16x8*)(Al + (i * 16 + l15) * 88 + koff);
                if (hi >= 2) v = 0;
                a[i] = v;
            }
            #pragma unroll
            for (int j = 0; j < 4; j++){
                bf16x8 v = *(const bf16x8*)(Btl + (wave * 64 + j * 16 + l15) * 88 + koff);
                if (hi >= 2) v = 0;
                bv[j] = v;
            }
        }
        #pragma unroll
        for (int i = 0; i < 5; i++)
            #pragma unroll
            for (int j = 0; j < 4; j++)
                acc[i][j] = __builtin_amdgcn_mfma_f32_16x16x32_bf16(a[i], bv[j], acc[i][j], 0, 0, 0);
    }

    #pragma unroll
    for (int i = 0; i < 5; i++){
        #pragma unroll
        for (int r = 0; r < 4; r++){
            int orow = i * 16 + hi * 4 + r;
            #pragma unroll
            for (int j = 0; j < 4; j++){
                int ocol = c0 + wave * 64 + j * 16 + l15;
                H[(size_t)b * 81920 + (size_t)orow * 1024 + ocol] =
                    __float2bfloat16(leaky(acc[i][j][r]));
            }
        }
    }
}

// ---------------- K3/K13: bf16 MFMA GEMM, Out = epi(A @ W [+Res]) ------------
template<int EPI>
__global__ __launch_bounds__(256) void k_gemm_mfma(const bf16* __restrict__ Abf,
                                                   const bf16* __restrict__ WT,
                                                   const float* __restrict__ Res,
                                                   void* __restrict__ Outv){
    __shared__ alignas(16) bf16 As[128 * 32];
    __shared__ alignas(16) bf16 Bs[128 * 32];
    const int K = 1024;
    int tid = threadIdx.x;
    int wave = tid >> 6, lane = tid & 63;
    int row0 = blockIdx.y * 128;
    int col0 = blockIdx.x * 128;

    const bf16* gA = Abf + (size_t)(row0 + (tid >> 2)) * K + (tid & 3) * 8;
    const bf16* gB = WT  + (size_t)(col0 + (tid >> 2)) * K + (tid & 3) * 8;
    bf16* dA0 = As + wave * 512;
    bf16* dA1 = As + 2048 + wave * 512;
    bf16* dB0 = Bs + wave * 512;
    bf16* dB1 = Bs + 2048 + wave * 512;

    int wr = (wave >> 1) * 64, wc = (wave & 1) * 64;
    const bf16* rA = As + (wr + (lane & 15)) * 32 + (lane >> 4) * 8;
    const bf16* rB = Bs + (wc + (lane & 15)) * 32 + (lane >> 4) * 8;

    f32x4 acc[4][4];
    #pragma unroll
    for (int i = 0; i < 4; i++)
        #pragma unroll
        for (int j = 0; j < 4; j++) acc[i][j] = (f32x4){0.f, 0.f, 0.f, 0.f};

    for (int k0 = 0; k0 < K; k0 += 32){
        gll16(gA + k0, dA0);
        gll16(gA + (size_t)64 * K + k0, dA1);
        gll16(gB + k0, dB0);
        gll16(gB + (size_t)64 * K + k0, dB1);
        __syncthreads();
        bf16x8 a[4], b[4];
        #pragma unroll
        for (int i = 0; i < 4; i++) a[i] = *(const bf16x8*)(rA + i * 512);
        #pragma unroll
        for (int j = 0; j < 4; j++) b[j] = *(const bf16x8*)(rB + j * 512);
        #pragma unroll
        for (int i = 0; i < 4; i++)
            #pragma unroll
            for (int j = 0; j < 4; j++)
                acc[i][j] = __builtin_amdgcn_mfma_f32_16x16x32_bf16(a[i], b[j], acc[i][j], 0, 0, 0);
        __syncthreads();
    }

    int orow = row0 + wr + (lane >> 4) * 4;
    int ocol = col0 + wc + (lane & 15);
    #pragma unroll
    for (int i = 0; i < 4; i++){
        #pragma unroll
        for (int r = 0; r < 4; r++){
            int rr = orow + i * 16 + r;
            #pragma unroll
            for (int j = 0; j < 4; j++){
                size_t o = (size_t)rr * 1024 + ocol + j * 16;
                float v = acc[i][j][r];
                if (EPI == 0) ((bf16*)Outv)[o] = __float2bfloat16(v + Res[o]);
                else          ((float*)Outv)[o] = leaky(v);
            }
        }
    }
}

// ---------------- K5: Out = A @ W^T + bias (small, fp32) ----------------
#define PAD 68
__global__ __launch_bounds__(256) void k_gemm_bt_bias(const float* __restrict__ Am,
                                                      const float* __restrict__ W,
                                                      const float* __restrict__ bias,
                                                      float* __restrict__ Out, int M){
    __shared__ float As[16][PAD];
    __shared__ float Bs[16][PAD];
    int tid = threadIdx.x;
    int tx = tid & 15, ty = tid >> 4;
    int row0 = blockIdx.y * 64, col0 = blockIdx.x * 64;
    float acc[4][4] = {};
    int lr = tid >> 2;
    int lk = (tid & 3) * 4;
    for (int k0 = 0; k0 < C_; k0 += 16){
        float4 av = *(const float4*)(Am + (size_t)(row0 + lr) * C_ + k0 + lk);
        float4 wv = *(const float4*)(W  + (size_t)(col0 + lr) * C_ + k0 + lk);
        As[lk + 0][lr] = av.x; As[lk + 1][lr] = av.y;
        As[lk + 2][lr] = av.z; As[lk + 3][lr] = av.w;
        Bs[lk + 0][lr] = wv.x; Bs[lk + 1][lr] = wv.y;
        Bs[lk + 2][lr] = wv.z; Bs[lk + 3][lr] = wv.w;
        __syncthreads();
        #pragma unroll
        for (int kk = 0; kk < 16; kk++){
            float4 a  = *(const float4*)&As[kk][ty * 4];
            float4 bb = *(const float4*)&Bs[kk][tx * 4];
            float ar[4] = {a.x, a.y, a.z, a.w};
            float br[4] = {bb.x, bb.y, bb.z, bb.w};
            #pragma unroll
            for (int i = 0; i < 4; i++)
                #pragma unroll
                for (int j = 0; j < 4; j++) acc[i][j] += ar[i] * br[j];
        }
        __syncthreads();
    }
    for (int i = 0; i < 4; i++){
        int r = row0 + ty * 4 + i;
        for (int j = 0; j < 4; j++){
            int cl = col0 + tx * 4 + j;
            Out[(size_t)r * C_ + cl] = acc[i][j] + bias[cl];
        }
    }
}

// ---------------- K4: glb0[b,c] = mean_n x2b[b,n,c] ----------------
__global__ void k_pool(const bf16* __restrict__ X2b, float* __restrict__ glb0){
    int b = blockIdx.x, c = blockIdx.y * 256 + threadIdx.x;
    const bf16* p = X2b + (size_t)b * 81920 + c;
    float s = 0.f;
    for (int nn = 0; nn < N_; nn++) s += __bfloat162float(p[nn * 1024]);
    glb0[b * C_ + c] = s * (1.f / N_);
}

// ---------------- K6: BN stats over batch ----------------
__global__ void k_bnstat(const float* __restrict__ g, float* __restrict__ mu,
                         float* __restrict__ rstd){
    int c = blockIdx.x * 256 + threadIdx.x;
    float s = 0.f, s2 = 0.f;
    for (int b = 0; b < B_; b++){ float v = g[b * C_ + c]; s += v; s2 += v * v; }
    float m = s * (1.f / B_);
    float var = s2 * (1.f / B_) - m * m;
    mu[c] = m;
    rstd[c] = rsqrtf(var + 1e-5f);
}

// ---------------- K7: glb2b = bf16(leaky(BN(glb1))) ----------------
__global__ void k_bnapply(const float* __restrict__ g, const float* __restrict__ mu,
                          const float* __restrict__ rstd, const float* __restrict__ gamma,
                          const float* __restrict__ beta, bf16* __restrict__ o){
    int i = blockIdx.x * 256 + threadIdx.x;
    int c = i & (C_ - 1);
    float v = (g[i] - mu[c]) * rstd[c] * gamma[c] + beta[c];
    o[i] = __float2bfloat16(leaky(v));
}

// ---------------- K9: dyn = sigmoid(ccw @ [glb2;x2[b]^T] + ccb), K=2048 ------
// 5 waves; wave w owns output rows n = 16w..16w+15, all 80 cols m.
// k<1024: B-operand is glb2b[b] (m-independent) -> direct global fragment load.
// k>=1024: B-operand rows m from X2b[b], LDS-staged.
__global__ __launch_bounds__(320) void k_dyn_mfma(const bf16* __restrict__ X2b,
                                                  const bf16* __restrict__ ccwb,
                                                  const bf16* __restrict__ glb2b,
                                                  const float* __restrict__ ccb,
                                                  float* __restrict__ dyn){
    __shared__ alignas(16) bf16 At[80 * 32];
    __shared__ alignas(16) bf16 Bt[80 * 32];
    int b = blockIdx.x, tid = threadIdx.x;
    int wave = tid >> 6, lane = tid & 63;
    int l15 = lane & 15, hi = lane >> 4;

    const bf16* gA = ccwb + (size_t)(wave * 16 + (lane >> 2)) * 2048 + (lane & 3) * 8;
    const bf16* gB = X2b + ((size_t)b * 80 + wave * 16 + (lane >> 2)) * 1024 + (lane & 3) * 8;
    const bf16* gG = glb2b + (size_t)b * 1024;
    bf16* dA = At + wave * 512;
    bf16* dB = Bt + wave * 512;

    f32x4 acc[5];
    #pragma unroll
    for (int j = 0; j < 5; j++) acc[j] = (f32x4){0.f, 0.f, 0.f, 0.f};

    for (int k0 = 0; k0 < 2048; k0 += 32){
        gll16(gA + k0, dA);
        if (k0 >= 1024) gll16(gB + (k0 - 1024), dB);
        __syncthreads();
        bf16x8 a = *(const bf16x8*)(At + (wave * 16 + l15) * 32 + hi * 8);
        bf16x8 bv[5];
        if (k0 < 1024){
            bf16x8 g = *(const bf16x8*)(gG + k0 + hi * 8);
            #pragma unroll
            for (int j = 0; j < 5; j++) bv[j] = g;
        } else {
            #pragma unroll
            for (int j = 0; j < 5; j++)
                bv[j] = *(const bf16x8*)(Bt + (j * 16 + l15) * 32 + hi * 8);
        }
        #pragma unroll
        for (int j = 0; j < 5; j++)
            acc[j] = __builtin_amdgcn_mfma_f32_16x16x32_bf16(a, bv[j], acc[j], 0, 0, 0);
        __syncthreads();
    }

    #pragma unroll
    for (int r = 0; r < 4; r++){
        int n = wave * 16 + hi * 4 + r;
        float cb = ccb[n];
        #pragma unroll
        for (int j = 0; j < 5; j++){
            int m = j * 16 + l15;
            dyn[(size_t)b * 6400 + n * N_ + m] = sigmoidf_(acc[j][r] + cb);
        }
    }
}

// ---------------- K10: loss rows + dinv ----------------
__global__ __launch_bounds__(128) void k_lossrow(const float* __restrict__ out1,
                                                 const float* __restrict__ dyn,
                                                 float* __restrict__ dinv,
                                                 float* __restrict__ lossp){
    __shared__ float o1s[N_];
    __shared__ float dd[N_];
    int b = blockIdx.x, t = threadIdx.x;
    if (t < N_) o1s[t] = sigmoidf_(out1[b * N_ + t]);
    __syncthreads();
    const float* db = dyn + (size_t)b * N_ * N_;
    if (t < N_){
        float acc = 0.f;
        for (int nn = 0; nn < N_; nn++) acc += o1s[nn] * db[nn * N_ + t];
        float tt = acc * (1.f / N_);
        float diff = o1s[t] - tt;
        dd[t] = diff * diff;
        float rs = 0.f;
        for (int m = 0; m < N_; m++) rs += db[t * N_ + m];
        dinv[b * N_ + t] = rsqrtf(rs);
    }
    __syncthreads();
    if (t == 0){
        float s = 0.f;
        for (int m = 0; m < N_; m++) s += dd[m];
        lossp[b] = sqrtf(s);
    }
}

// ---------------- K11: loss = sum(lossp) ----------------
__global__ void k_lsum(const float* __restrict__ lossp, float* __restrict__ out_loss){
    float v = lossp[threadIdx.x];
    for (int off = 32; off; off >>= 1) v += __shfl_down(v, off);
    __shared__ float wsum[4];
    int lane = threadIdx.x & 63, w = threadIdx.x >> 6;
    if (lane == 0) wsum[w] = v;
    __syncthreads();
    if (threadIdx.x == 0) out_loss[0] = wsum[0] + wsum[1] + wsum[2] + wsum[3];
}

// ---------------- K12a: ADJD[b][n][m] = bf16(di[n]*dyn[b][m][n]*di[m]) -------
__global__ void k_adjs_d(const float* __restrict__ dyn, const float* __restrict__ dinv,
                         bf16* __restrict__ ADJD){
    __shared__ float di[N_];
    int b = blockIdx.x, tid = threadIdx.x;
    if (tid < N_) di[tid] = dinv[b * N_ + tid];
    __syncthreads();
    const float* db = dyn + (size_t)b * 6400;
    bf16* ab = ADJD + (size_t)b * 80 * 88;
    for (int idx = tid; idx < 6400; idx += 256){
        int n = idx / 80, m = idx - n * 80;
        ab[n * 88 + m] = __float2bfloat16(di[n] * db[m * 80 + n] * di[m]);
    }
}

extern "C" void kernel_launch(void* const* d_in, const int* in_sizes, int n_in,
                              void* d_out, int out_size, void* d_ws, size_t ws_size,
                              hipStream_t stream) {
    const float* x     = (const float*)d_in[0];
    const float* out1  = (const float*)d_in[1];
    const float* A     = (const float*)d_in[2];
    const float* sw    = (const float*)d_in[3];
    const float* cgw   = (const float*)d_in[4];
    const float* cgb   = (const float*)d_in[5];
    const float* gamma = (const float*)d_in[6];
    const float* beta  = (const float*)d_in[7];
    const float* ccw   = (const float*)d_in[8];
    const float* ccb   = (const float*)d_in[9];
    const float* dw    = (const float*)d_in[10];
    float* out = (float*)d_out;

    const size_t XN = (size_t)B_ * N_ * C_;   // 20,971,520
    char* p = (char*)d_ws;
    bf16*  Hbf  = (bf16*)p;   p += XN * 2;               // 42 MB
    bf16*  X2b  = (bf16*)p;   p += XN * 2;               // 42 MB
    bf16*  SWT  = (bf16*)p;   p += (size_t)C_ * C_ * 2;  // 2 MB
    bf16*  DWT  = (bf16*)p;   p += (size_t)C_ * CO_ * 2; // 2 MB
    bf16*  CCWB = (bf16*)p;   p += (size_t)N_ * 2048 * 2;
    bf16*  ADJS = (bf16*)p;   p += (size_t)80 * 88 * 2;
    bf16*  ADJD = (bf16*)p;   p += (size_t)B_ * 80 * 88 * 2;  // 3.6 MB
    float* GLB0 = (float*)p;  p += (size_t)B_ * C_ * 4;
    float* GLB1 = (float*)p;  p += (size_t)B_ * C_ * 4;
    bf16*  GLB2 = (bf16*)p;   p += (size_t)B_ * C_ * 2;
    float* MU   = (float*)p;  p += C_ * 4;
    float* RSTD = (float*)p;  p += C_ * 4;
    float* DYN  = (float*)p;  p += (size_t)B_ * N_ * N_ * 4;  // 6.55 MB
    float* DINV = (float*)p;  p += (size_t)B_ * N_ * 4;
    float* LOSSP= (float*)p;  p += B_ * 4;

    const int M = B_ * N_;                     // 20480

    k_convT<<<dim3(32, 32), 256, 0, stream>>>(sw, SWT);
    k_convT<<<dim3(32, 32), 256, 0, stream>>>(dw, DWT);
    k_cvt_ccw<<<(N_ * 2048) / 256, 256, 0, stream>>>(ccw, CCWB);
    k_adj<<<1, 256, 0, stream>>>(A, ADJS);
    k_prop_mfma<0><<<dim3(B_, 4), 256, 0, stream>>>(x, ADJS, Hbf);
    k_gemm_mfma<0><<<dim3(C_ / 128, M / 128), 256, 0, stream>>>(Hbf, SWT, x, X2b);
    k_pool<<<dim3(B_, C_ / 256), 256, 0, stream>>>(X2b, GLB0);
    k_gemm_bt_bias<<<dim3(C_ / 64, B_ / 64), 256, 0, stream>>>(GLB0, cgw, cgb, GLB1, B_);
    k_bnstat<<<C_ / 256, 256, 0, stream>>>(GLB1, MU, RSTD);
    k_bnapply<<<(B_ * C_) / 256, 256, 0, stream>>>(GLB1, MU, RSTD, gamma, beta, GLB2);
    k_dyn_mfma<<<B_, 320, 0, stream>>>(X2b, CCWB, GLB2, ccb, DYN);
    k_lossrow<<<B_, 128, 0, stream>>>(out1, DYN, DINV, LOSSP);
    k_lsum<<<1, 256, 0, stream>>>(LOSSP, out + (size_t)B_ * N_ * CO_);
    k_adjs_d<<<B_, 256, 0, stream>>>(DYN, DINV, ADJD);
    k_prop_mfma<1><<<dim3(B_, 4), 256, 0, stream>>>(X2b, ADJD, Hbf);
    k_gemm_mfma<1><<<dim3(CO_ / 128, M / 128), 256, 0, stream>>>(Hbf, DWT, nullptr, out);
}